// Round 17
// baseline (103.024 us; speedup 1.0000x reference)
//
#include <hip/hip_runtime.h>

#define NNODES 100000
#define NEDGES 500000
#define DD 128
#define NBUK 3125      // 32-node combined buckets: 100000/32 exactly
#define BCAP 512       // mean 320, sigma ~18 -> +10.7 sigma
#define BINB 123       // bin blocks (123 * 8192 >= 1M edges)
#define ZBYTE ((unsigned int)NNODES << 8)  // byte offset of zero row in xb

typedef __attribute__((ext_vector_type(8))) short short8v;
typedef __attribute__((ext_vector_type(4))) float f32x4;

__device__ __forceinline__ unsigned short f2bf(float f) {
    unsigned int u = __float_as_uint(f);
    return (unsigned short)((u + 0x7FFFu + ((u >> 16) & 1u)) >> 16);
}
__device__ __forceinline__ unsigned int f2bf2(float a, float b) {
    return (unsigned int)f2bf(a) | ((unsigned int)f2bf(b) << 16);
}
__device__ __forceinline__ float bflo(unsigned int v) {
    return __uint_as_float(v << 16);
}
__device__ __forceinline__ float bfhi(unsigned int v) {
    return __uint_as_float(v & 0xFFFF0000u);
}

// ---------------------------------------------------------------------------
// Init: blocks [0,13) zero the 3125 bucket cursors; block 13 detects int64
// vs int32 edge storage (odd 32-bit words all zero => int64).
// ---------------------------------------------------------------------------
__global__ __launch_bounds__(256) void init_kernel(
        int* __restrict__ gcur, const unsigned int* __restrict__ e,
        int* __restrict__ flag) {
    if (blockIdx.x < 13) {
        const int i = blockIdx.x * 256 + threadIdx.x;
        if (i < NBUK) gcur[i] = 0;
        return;
    }
    __shared__ unsigned int s_acc;
    if (threadIdx.x == 0) s_acc = 0u;
    __syncthreads();
    unsigned int v = 0u;
    for (int i = threadIdx.x; i < 4096; i += 256)
        v |= e[2 * i + 1];
    for (int off = 32; off > 0; off >>= 1)
        v |= __shfl_down(v, off, 64);
    if ((threadIdx.x & 63) == 0) atomicOr(&s_acc, v);
    __syncthreads();
    if (threadIdx.x == 0) *flag = (s_acc == 0u) ? 1 : 0;
}

// ---------------------------------------------------------------------------
// Fused prep. Block roles:
//   [0,BINB):      edge binning, 8192 edges/block, both passes batched 8-deep.
//                  Entry = (src<<8) | (d&31)<<1 | list  (bits 6-7 zero;
//                  row byte offset = ent & ~255, seg = ent & 63).
//   [BINB,+24):    W (fp32 [384][128]) -> fragment-packed bf16 wb.
//   BINB+24:       zero row of xb at index NNODES (pad-load target).
//   [BINB+25,+512): x (fp32) -> xb (bf16 row-major).
// ---------------------------------------------------------------------------
__global__ __launch_bounds__(256) void prep_kernel(
        const float4* __restrict__ x4, uint2* __restrict__ xb2,
        const float* __restrict__ W, unsigned short* __restrict__ wb,
        const void* __restrict__ pe, const void* __restrict__ ne,
        const int* __restrict__ flag,
        int* __restrict__ gcur, unsigned int* __restrict__ regions) {
    const int b = blockIdx.x;
    if (b < BINB) {
        __shared__ int hist[NBUK];
        __shared__ int gbase[NBUK];
        const int tid = threadIdx.x;
        for (int i = tid; i < NBUK; i += 256) hist[i] = 0;
        __syncthreads();
        const int e0 = b * 8192;
        const int fl = *flag;
        // pass 1: LDS histogram of bucket ids, 8-deep batched loads
        for (int k0 = 0; k0 < 32; k0 += 8) {
            int dv[8];
            bool ok[8];
#pragma unroll
            for (int j = 0; j < 8; ++j) {
                const int i = e0 + (k0 + j) * 256 + tid;
                ok[j] = i < 2 * NEDGES;
                const int ic = ok[j] ? i : 0;
                const int list = ic >= NEDGES;
                const int e = ic - list * NEDGES;
                const void* ed = list ? ne : pe;
                dv[j] = fl ? (int)((const long long*)ed)[NEDGES + e]
                           : ((const int*)ed)[NEDGES + e];
            }
#pragma unroll
            for (int j = 0; j < 8; ++j)
                if (ok[j]) atomicAdd(&hist[dv[j] >> 5], 1);
        }
        __syncthreads();
        // reserve: one global atomic per (block,bucket)
        for (int i = tid; i < NBUK; i += 256) {
            const int h = hist[i];
            gbase[i] = h ? atomicAdd(&gcur[i], h) : 0;
            hist[i] = 0;  // reuse as local cursor
        }
        __syncthreads();
        // pass 2: place entries, 8-deep batched
        for (int k0 = 0; k0 < 32; k0 += 8) {
            unsigned int ent[8];
            int bk[8];
            bool ok[8];
#pragma unroll
            for (int j = 0; j < 8; ++j) {
                const int i = e0 + (k0 + j) * 256 + tid;
                ok[j] = i < 2 * NEDGES;
                const int ic = ok[j] ? i : 0;
                const int list = ic >= NEDGES;
                const int e = ic - list * NEDGES;
                int s, d;
                if (fl) {
                    const long long* p = (const long long*)(list ? ne : pe);
                    s = (int)p[e]; d = (int)p[NEDGES + e];
                } else {
                    const int* p = (const int*)(list ? ne : pe);
                    s = p[e]; d = p[NEDGES + e];
                }
                bk[j] = d >> 5;
                ent[j] = ((unsigned int)s << 8) |
                         ((unsigned int)(d & 31) << 1) | (unsigned int)list;
            }
            int pos[8];
#pragma unroll
            for (int j = 0; j < 8; ++j)
                if (ok[j]) pos[j] = gbase[bk[j]] + atomicAdd(&hist[bk[j]], 1);
#pragma unroll
            for (int j = 0; j < 8; ++j)
                if (ok[j] && pos[j] < BCAP)
                    regions[(size_t)bk[j] * BCAP + pos[j]] = ent[j];
        }
    } else if (b < BINB + 24) {
        // frag (s,nf) at ((s*8+nf)*64+lane)*8 shorts; lane l holds
        // B[k=32s+(l>>4)*8+j][n=16nf+(l&15)], j=0..7.
        const int t = (b - BINB) * 256 + threadIdx.x;
        const int l = t & 63;
        const int nf = (t >> 6) & 7;
        const int s = t >> 9;
        const int n = nf * 16 + (l & 15);
        const int k0 = s * 32 + (l >> 4) * 8;
        unsigned short* o = wb + (size_t)t * 8;
#pragma unroll
        for (int j = 0; j < 8; ++j)
            o[j] = f2bf(W[(size_t)(k0 + j) * DD + n]);
    } else if (b == BINB + 24) {
        if (threadIdx.x < 64)
            ((unsigned int*)xb2)[(size_t)NNODES * 64 + threadIdx.x] = 0u;
    } else {
        const int n = NNODES * DD / 4;
        for (int i = (b - BINB - 25) * 256 + threadIdx.x; i < n; i += 512 * 256) {
            const float4 v = x4[i];
            uint2 o;
            o.x = f2bf2(v.x, v.y);
            o.y = f2bf2(v.z, v.w);
            xb2[i] = o;
        }
    }
}

// ---------------------------------------------------------------------------
// Fused aggregate + GEMM: one block per 32-node bucket, 256 threads (4 waves),
// ~19.7 KB LDS -> 8 blocks/CU (32 waves/CU) with 8 INDEPENDENT blocks
// interleaving gather and MFMA phases (restores R9's block-level overlap).
// Preamble (5 barriers): B1 cnt-zero; hist; B2; wave0 64-lane shfl scan ||
// waves1-3 zero tile; B3; place; B4; [c=0 MFMA early]; flat gather; B5;
// c=1/2 MFMA tail. 3125*32 = 100000 exactly -> no row guards anywhere.
// ---------------------------------------------------------------------------
__global__ __launch_bounds__(256) void aggemm_kernel(
        const char* __restrict__ xbb,
        const int* __restrict__ gcur, const unsigned int* __restrict__ regions,
        const unsigned short* __restrict__ wb,
        const float* __restrict__ bias,
        float* __restrict__ out) {
    __shared__ unsigned short tile[32 * 264];  // 16.9 KB, pitch 528B
    __shared__ unsigned int sorted[BCAP];      // 2 KB
    __shared__ int cnt[64];
    __shared__ int sstart[65];
    __shared__ int scur[64];

    const int b = blockIdx.x;
    const int node0 = b * 32;
    const int tid = threadIdx.x;
    const int wid = tid >> 6;      // 0..3
    const int lane = tid & 63;

    int n = gcur[b];
    n = n < BCAP ? n : BCAP;
    const unsigned int* __restrict__ reg = regions + (size_t)b * BCAP;

    // --- prefetch c=0 A-frags immediately (complete during preamble) ---
    const int lm = lane & 15;
    const int lk = lane >> 4;
    const int rg = wid & 1;        // row group (16 rows)
    const int ch = wid >> 1;       // col half (64 cols = 4 n-frags)
    const int rl0 = rg * 16;
    const int rowg = node0 + rl0 + lm;   // always < NNODES (3125*32 = 100000)
    const unsigned short* __restrict__ xb = (const unsigned short*)xbb;
    short8v a0pre[4];
#pragma unroll
    for (int s = 0; s < 4; ++s)
        a0pre[s] = *(const short8v*)(xb + (size_t)rowg * 128 + s * 32 + lk * 8);

    if (tid < 64) cnt[tid] = 0;
    __syncthreads();                                             // B1
    for (int i = tid; i < n; i += 256)
        atomicAdd(&cnt[reg[i] & 63u], 1);
    __syncthreads();                                             // B2

    unsigned int* tileW = (unsigned int*)tile;
    if (wid == 0) {
        // 64-count exclusive scan in one wave (shfl, no barriers)
        const int c = cnt[lane];
        int x = c;
#pragma unroll
        for (int off = 1; off < 64; off <<= 1) {
            const int y = __shfl_up(x, off, 64);
            if (lane >= off) x += y;
        }
        sstart[lane] = x - c;
        scur[lane] = x - c;
        if (lane == 63) sstart[64] = x;
    } else {
        // waves 1-3 zero the tile meanwhile (32 rows x 132 words)
        for (int i = tid - 64; i < 32 * 132; i += 192)
            tileW[i] = 0u;
    }
    __syncthreads();                                             // B3
    for (int i = tid; i < n; i += 256) {
        const unsigned int ent = reg[i];
        const int pos = atomicAdd(&scur[ent & 63u], 1);
        sorted[pos] = ent;                       // already src*256 | seg
    }
    __syncthreads();                                             // B4

    // --- c=0 MFMA early: depends only on a0pre; overlaps gather latency ---
    f32x4 acc[4];
#pragma unroll
    for (int nf = 0; nf < 4; ++nf) acc[nf] = (f32x4)(0.f);
#pragma unroll
    for (int s = 0; s < 4; ++s) {
        const short8v* __restrict__ bp =
            (const short8v*)wb + ((size_t)(s * 8 + ch * 4)) * 64 + lane;
#pragma unroll
        for (int nf = 0; nf < 4; ++nf)
            acc[nf] = __builtin_amdgcn_mfma_f32_16x16x32_bf16(
                a0pre[s], bp[nf * 64], acc[nf], 0, 0, 0);
    }

    // --- flat gather: wave w streams segs [16w,16w+16) as one range ---
    const int lo = sstart[wid * 16];
    const int hi = sstart[wid * 16 + 16];
    const unsigned int lane4 = lane * 4;
    unsigned int cur = 255u;
    float ax = 0.f, ay = 0.f;
    for (int base = lo; base < hi; base += 8) {
        unsigned int ent[8];
#pragma unroll
        for (int j = 0; j < 8; ++j) {
            const int ii = base + j;
            ent[j] = (ii < hi) ? sorted[ii] : (ZBYTE | 255u);
        }
        unsigned int v[8];
#pragma unroll
        for (int j = 0; j < 8; ++j)
            v[j] = *(const unsigned int*)(
                xbb + (size_t)((ent[j] & 0xFFFFFF00u) + lane4));
#pragma unroll
        for (int j = 0; j < 8; ++j) {
            const unsigned int s = ent[j] & 255u;  // real seg <= 63; pad = 255
            if (s != cur) {                        // wave-uniform branch
                if (cur != 255u)
                    tileW[(cur >> 1) * 132 + (cur & 1) * 64 + lane] =
                        f2bf2(ax, ay);
                cur = s;
                ax = 0.f;
                ay = 0.f;
            }
            ax += bflo(v[j]);
            ay += bfhi(v[j]);
        }
    }
    if (cur != 255u)
        tileW[(cur >> 1) * 132 + (cur & 1) * 64 + lane] = f2bf2(ax, ay);
    __syncthreads();                                             // B5

    // --- c=1/2 MFMA tail ---
    for (int c = 1; c < 3; ++c) {
#pragma unroll
        for (int s = 0; s < 4; ++s) {
            const short8v a = *(const short8v*)(tile + (rl0 + lm) * 264 +
                                                (c - 1) * 128 + s * 32 + lk * 8);
            const short8v* __restrict__ bp =
                (const short8v*)wb + ((size_t)((c * 4 + s) * 8 + ch * 4)) * 64 + lane;
#pragma unroll
            for (int nf = 0; nf < 4; ++nf)
                acc[nf] = __builtin_amdgcn_mfma_f32_16x16x32_bf16(
                    a, bp[nf * 64], acc[nf], 0, 0, 0);
        }
    }

    const int rbase = node0 + rl0 + lk * 4;
#pragma unroll
    for (int nf = 0; nf < 4; ++nf) {
        const int col = (ch * 4 + nf) * 16 + lm;
        const float bv = bias[col];
#pragma unroll
        for (int r = 0; r < 4; ++r)
            out[(size_t)(rbase + r) * 128 + col] = acc[nf][r] + bv;
    }
}

extern "C" void kernel_launch(void* const* d_in, const int* in_sizes, int n_in,
                              void* d_out, int out_size, void* d_ws, size_t ws_size,
                              hipStream_t stream) {
    const float* x     = (const float*)d_in[0];
    const void*  pos_e = d_in[1];
    const void*  neg_e = d_in[2];
    const float* W     = (const float*)d_in[3];
    const float* bias  = (const float*)d_in[4];
    float*       out   = (float*)d_out;

    const size_t XB = ((size_t)NNODES + 2) * DD * 2;   // 25.6 MB + zero row
    const size_t WB = 12 * 8 * 64 * 8 * 2;             // 98304 B
    const size_t GB = 16384;                           // cursors (NBUK ints)
    const size_t RB = (size_t)NBUK * BCAP * 4;         // 6.4 MB regions

    char* ws = (char*)d_ws;
    int* flag = (int*)ws;
    size_t off = 256;
    unsigned int*   xb      = (unsigned int*)(ws + off);   off += XB;
    unsigned short* wb      = (unsigned short*)(ws + off); off += WB;
    int*            gcur    = (int*)(ws + off);            off += GB;
    unsigned int*   regions = (unsigned int*)(ws + off);   off += RB;
    (void)ws_size;

    init_kernel<<<14, 256, 0, stream>>>(gcur, (const unsigned int*)pos_e, flag);

    prep_kernel<<<BINB + 25 + 512, 256, 0, stream>>>(
        (const float4*)x, (uint2*)xb, W, wb, pos_e, neg_e, flag, gcur, regions);

    aggemm_kernel<<<NBUK, 256, 0, stream>>>(
        (const char*)xb, gcur, regions, wb, bias, out);
}

// Round 18
// 97.757 us; speedup vs baseline: 1.0539x; 1.0539x over previous
//
#include <hip/hip_runtime.h>

#define NNODES 100000
#define NEDGES 500000
#define DD 128
#define NBUK 1563      // 64-node combined buckets: ceil(100000/64)
#define BCAP 896       // mean 640, sigma 25 -> +10 sigma
#define BINB 123       // bin blocks (123 * 8192 >= 1M edges)
#define ZBYTE ((unsigned int)NNODES << 8)  // byte offset of zero row in xb

typedef __attribute__((ext_vector_type(8))) short short8v;
typedef __attribute__((ext_vector_type(4))) float f32x4;

__device__ __forceinline__ unsigned short f2bf(float f) {
    unsigned int u = __float_as_uint(f);
    return (unsigned short)((u + 0x7FFFu + ((u >> 16) & 1u)) >> 16);
}
__device__ __forceinline__ unsigned int f2bf2(float a, float b) {
    return (unsigned int)f2bf(a) | ((unsigned int)f2bf(b) << 16);
}
__device__ __forceinline__ float bflo(unsigned int v) {
    return __uint_as_float(v << 16);
}
__device__ __forceinline__ float bfhi(unsigned int v) {
    return __uint_as_float(v & 0xFFFF0000u);
}

// ---------------------------------------------------------------------------
// Init: blocks [0,7) zero the 1563 bucket cursors; block 7 detects int64 vs
// int32 edge storage (odd 32-bit words all zero => int64).
// ---------------------------------------------------------------------------
__global__ __launch_bounds__(256) void init_kernel(
        int* __restrict__ gcur, const unsigned int* __restrict__ e,
        int* __restrict__ flag) {
    if (blockIdx.x < 7) {
        const int i = blockIdx.x * 256 + threadIdx.x;
        if (i < NBUK) gcur[i] = 0;
        return;
    }
    __shared__ unsigned int s_acc;
    if (threadIdx.x == 0) s_acc = 0u;
    __syncthreads();
    unsigned int v = 0u;
    for (int i = threadIdx.x; i < 4096; i += 256)
        v |= e[2 * i + 1];
    for (int off = 32; off > 0; off >>= 1)
        v |= __shfl_down(v, off, 64);
    if ((threadIdx.x & 63) == 0) atomicOr(&s_acc, v);
    __syncthreads();
    if (threadIdx.x == 0) *flag = (s_acc == 0u) ? 1 : 0;
}

// ---------------------------------------------------------------------------
// Fused prep. Block roles:
//   [0,BINB):      edge binning, 8192 edges/block, both passes batched 8-deep.
//                  Entry = (src<<8) | (d&63)<<1 | list  (bit 7 always 0;
//                  row byte offset = ent & ~255, seg = ent & 127).
//   [BINB,+24):    W (fp32 [384][128]) -> fragment-packed bf16 wb.
//   BINB+24:       zero row of xb at index NNODES (padding/clamp target).
//   [BINB+25,+512): x (fp32) -> xb (bf16 row-major).
// ---------------------------------------------------------------------------
__global__ __launch_bounds__(256) void prep_kernel(
        const float4* __restrict__ x4, uint2* __restrict__ xb2,
        const float* __restrict__ W, unsigned short* __restrict__ wb,
        const void* __restrict__ pe, const void* __restrict__ ne,
        const int* __restrict__ flag,
        int* __restrict__ gcur, unsigned int* __restrict__ regions) {
    const int b = blockIdx.x;
    if (b < BINB) {
        __shared__ int hist[NBUK];
        __shared__ int gbase[NBUK];
        const int tid = threadIdx.x;
        for (int i = tid; i < NBUK; i += 256) hist[i] = 0;
        __syncthreads();
        const int e0 = b * 8192;
        const int fl = *flag;
        // pass 1: LDS histogram of bucket ids, 8-deep batched loads
        for (int k0 = 0; k0 < 32; k0 += 8) {
            int dv[8];
            bool ok[8];
#pragma unroll
            for (int j = 0; j < 8; ++j) {
                const int i = e0 + (k0 + j) * 256 + tid;
                ok[j] = i < 2 * NEDGES;
                const int ic = ok[j] ? i : 0;
                const int list = ic >= NEDGES;
                const int e = ic - list * NEDGES;
                const void* ed = list ? ne : pe;
                dv[j] = fl ? (int)((const long long*)ed)[NEDGES + e]
                           : ((const int*)ed)[NEDGES + e];
            }
#pragma unroll
            for (int j = 0; j < 8; ++j)
                if (ok[j]) atomicAdd(&hist[dv[j] >> 6], 1);
        }
        __syncthreads();
        // reserve: one global atomic per (block,bucket)
        for (int i = tid; i < NBUK; i += 256) {
            const int h = hist[i];
            gbase[i] = h ? atomicAdd(&gcur[i], h) : 0;
            hist[i] = 0;  // reuse as local cursor
        }
        __syncthreads();
        // pass 2: place entries, 8-deep batched
        for (int k0 = 0; k0 < 32; k0 += 8) {
            unsigned int ent[8];
            int bk[8];
            bool ok[8];
#pragma unroll
            for (int j = 0; j < 8; ++j) {
                const int i = e0 + (k0 + j) * 256 + tid;
                ok[j] = i < 2 * NEDGES;
                const int ic = ok[j] ? i : 0;
                const int list = ic >= NEDGES;
                const int e = ic - list * NEDGES;
                int s, d;
                if (fl) {
                    const long long* p = (const long long*)(list ? ne : pe);
                    s = (int)p[e]; d = (int)p[NEDGES + e];
                } else {
                    const int* p = (const int*)(list ? ne : pe);
                    s = p[e]; d = p[NEDGES + e];
                }
                bk[j] = d >> 6;
                ent[j] = ((unsigned int)s << 8) |
                         ((unsigned int)(d & 63) << 1) | (unsigned int)list;
            }
            int pos[8];
#pragma unroll
            for (int j = 0; j < 8; ++j)
                if (ok[j]) pos[j] = gbase[bk[j]] + atomicAdd(&hist[bk[j]], 1);
#pragma unroll
            for (int j = 0; j < 8; ++j)
                if (ok[j] && pos[j] < BCAP)
                    regions[(size_t)bk[j] * BCAP + pos[j]] = ent[j];
        }
    } else if (b < BINB + 24) {
        // frag (s,nf) at ((s*8+nf)*64+lane)*8 shorts; lane l holds
        // B[k=32s+(l>>4)*8+j][n=16nf+(l&15)], j=0..7.
        const int t = (b - BINB) * 256 + threadIdx.x;
        const int l = t & 63;
        const int nf = (t >> 6) & 7;
        const int s = t >> 9;
        const int n = nf * 16 + (l & 15);
        const int k0 = s * 32 + (l >> 4) * 8;
        unsigned short* o = wb + (size_t)t * 8;
#pragma unroll
        for (int j = 0; j < 8; ++j)
            o[j] = f2bf(W[(size_t)(k0 + j) * DD + n]);
    } else if (b == BINB + 24) {
        if (threadIdx.x < 64)
            ((unsigned int*)xb2)[(size_t)NNODES * 64 + threadIdx.x] = 0u;
    } else {
        const int n = NNODES * DD / 4;
        for (int i = (b - BINB - 25) * 256 + threadIdx.x; i < n; i += 512 * 256) {
            const float4 v = x4[i];
            uint2 o;
            o.x = f2bf2(v.x, v.y);
            o.y = f2bf2(v.z, v.w);
            xb2[i] = o;
        }
    }
}

// ---------------------------------------------------------------------------
// Fused aggregate + GEMM: one block per 64-node bucket, 512 threads (8 waves).
// Preamble (5 barriers): B1 cnt-zero; hist; B2; wave0 shfl-scan || waves1-7
// zero tile; B3; place; B4; [c=0 MFMA early]; gather; B5; c=1/2 MFMA.
// c=0 MFMA (x@W0) depends only on the prefetched a0pre frags, so it runs
// BEFORE the gather — its MFMA+B-frag-load latency overlaps other waves'
// gather loads, and the post-B5 tail shrinks from 48 to 32 MFMAs.
// Gather: flat stream of sorted entries, 8-deep; seg transitions are
// wave-uniform; flush is a direct store; pad sentinel has bit7 set
// (s = ent&255 = 255 > any real seg <= 127) so pads are never flushed.
// ---------------------------------------------------------------------------
__global__ __launch_bounds__(512) void aggemm_kernel(
        const char* __restrict__ xbb,
        const int* __restrict__ gcur, const unsigned int* __restrict__ regions,
        const unsigned short* __restrict__ wb,
        const float* __restrict__ bias,
        float* __restrict__ out) {
    __shared__ unsigned short tile[64 * 264];  // 33.8 KB, pitch 528B
    __shared__ unsigned int sorted[BCAP];
    __shared__ int cnt[128];
    __shared__ int sstart[129];
    __shared__ int scur[128];

    const int b = blockIdx.x;
    const int node0 = b * 64;
    const int tid = threadIdx.x;
    const int wid = tid >> 6;
    const int lane = tid & 63;

    int n = gcur[b];
    n = n < BCAP ? n : BCAP;
    const unsigned int* __restrict__ reg = regions + (size_t)b * BCAP;

    // --- prefetch c=0 A-frags immediately (complete during preamble) ---
    const int lm = lane & 15;
    const int lk = lane >> 4;
    const int rg = wid & 3;        // row group (16 rows)
    const int ch = wid >> 2;       // col half (64 cols = 4 n-frags)
    const int rl0 = rg * 16;
    int rowg = node0 + rl0 + lm;
    if (rowg > NNODES) rowg = NNODES;  // clamp into zero row
    const unsigned short* __restrict__ xb = (const unsigned short*)xbb;
    short8v a0pre[4];
#pragma unroll
    for (int s = 0; s < 4; ++s)
        a0pre[s] = *(const short8v*)(xb + (size_t)rowg * 128 + s * 32 + lk * 8);

    if (tid < 128) cnt[tid] = 0;
    __syncthreads();                                             // B1
    for (int i = tid; i < n; i += 512)
        atomicAdd(&cnt[reg[i] & 127u], 1);
    __syncthreads();                                             // B2

    unsigned int* tileW = (unsigned int*)tile;
    if (wid == 0) {
        // single-wave exclusive scan of 128 counts, shfl-based (no barriers)
        const int c0 = cnt[lane * 2];
        const int c1 = cnt[lane * 2 + 1];
        const int s = c0 + c1;
        int x = s;
#pragma unroll
        for (int off = 1; off < 64; off <<= 1) {
            const int y = __shfl_up(x, off, 64);
            if (lane >= off) x += y;
        }
        const int excl = x - s;
        sstart[lane * 2] = excl;
        scur[lane * 2] = excl;
        sstart[lane * 2 + 1] = excl + c0;
        scur[lane * 2 + 1] = excl + c0;
        if (lane == 63) sstart[128] = x;
    } else {
        // waves 1-7 zero the tile meanwhile (64 rows x 132 words over 7 waves)
        for (int i = tid - 64; i < 64 * 132; i += 448)
            tileW[i] = 0u;
    }
    __syncthreads();                                             // B3
    for (int i = tid; i < n; i += 512) {
        const unsigned int ent = reg[i];
        const int pos = atomicAdd(&scur[ent & 127u], 1);
        sorted[pos] = ent;                       // already src*256 | seg
    }
    __syncthreads();                                             // B4

    // --- c=0 MFMA early: depends only on a0pre; overlaps gather latency ---
    f32x4 acc[4];
#pragma unroll
    for (int nf = 0; nf < 4; ++nf) acc[nf] = (f32x4)(0.f);
#pragma unroll
    for (int s = 0; s < 4; ++s) {
        const short8v* __restrict__ bp =
            (const short8v*)wb + ((size_t)(s * 8 + ch * 4)) * 64 + lane;
#pragma unroll
        for (int nf = 0; nf < 4; ++nf)
            acc[nf] = __builtin_amdgcn_mfma_f32_16x16x32_bf16(
                a0pre[s], bp[nf * 64], acc[nf], 0, 0, 0);
    }

    // --- flat gather ---
    const int lo = sstart[wid * 16];
    const int hi = sstart[wid * 16 + 16];
    const unsigned int lane4 = lane * 4;
    unsigned int cur = 255u;
    float ax = 0.f, ay = 0.f;
    for (int base = lo; base < hi; base += 8) {
        unsigned int ent[8];
#pragma unroll
        for (int j = 0; j < 8; ++j) {
            const int ii = base + j;
            ent[j] = (ii < hi) ? sorted[ii] : (ZBYTE | 255u);
        }
        unsigned int v[8];
#pragma unroll
        for (int j = 0; j < 8; ++j)
            v[j] = *(const unsigned int*)(
                xbb + (size_t)((ent[j] & 0xFFFFFF00u) + lane4));
#pragma unroll
        for (int j = 0; j < 8; ++j) {
            const unsigned int s = ent[j] & 255u;
            if (s != cur) {                      // wave-uniform branch
                if (cur != 255u)
                    tileW[(cur >> 1) * 132 + (cur & 1) * 64 + lane] =
                        f2bf2(ax, ay);
                cur = s;
                ax = 0.f;
                ay = 0.f;
            }
            ax += bflo(v[j]);
            ay += bfhi(v[j]);
        }
    }
    if (cur != 255u)
        tileW[(cur >> 1) * 132 + (cur & 1) * 64 + lane] = f2bf2(ax, ay);
    __syncthreads();                                             // B5

    // --- c=1/2 MFMA tail ---
    for (int c = 1; c < 3; ++c) {
#pragma unroll
        for (int s = 0; s < 4; ++s) {
            const short8v a = *(const short8v*)(tile + (rl0 + lm) * 264 +
                                                (c - 1) * 128 + s * 32 + lk * 8);
            const short8v* __restrict__ bp =
                (const short8v*)wb + ((size_t)((c * 4 + s) * 8 + ch * 4)) * 64 + lane;
#pragma unroll
            for (int nf = 0; nf < 4; ++nf)
                acc[nf] = __builtin_amdgcn_mfma_f32_16x16x32_bf16(
                    a, bp[nf * 64], acc[nf], 0, 0, 0);
        }
    }

    const int rbase = node0 + rl0 + lk * 4;
#pragma unroll
    for (int nf = 0; nf < 4; ++nf) {
        const int col = (ch * 4 + nf) * 16 + lm;
        const float bv = bias[col];
#pragma unroll
        for (int r = 0; r < 4; ++r) {
            const int row = rbase + r;
            if (row < NNODES)
                out[(size_t)row * 128 + col] = acc[nf][r] + bv;
        }
    }
}

extern "C" void kernel_launch(void* const* d_in, const int* in_sizes, int n_in,
                              void* d_out, int out_size, void* d_ws, size_t ws_size,
                              hipStream_t stream) {
    const float* x     = (const float*)d_in[0];
    const void*  pos_e = d_in[1];
    const void*  neg_e = d_in[2];
    const float* W     = (const float*)d_in[3];
    const float* bias  = (const float*)d_in[4];
    float*       out   = (float*)d_out;

    const size_t XB = ((size_t)NNODES + 2) * DD * 2;   // 25.6 MB + zero row + slack
    const size_t WB = 12 * 8 * 64 * 8 * 2;             // 98304 B
    const size_t GB = 8192;                            // cursors (NBUK ints)
    const size_t RB = (size_t)NBUK * BCAP * 4;         // 5.6 MB regions

    char* ws = (char*)d_ws;
    int* flag = (int*)ws;
    size_t off = 256;
    unsigned int*   xb      = (unsigned int*)(ws + off);   off += XB;
    unsigned short* wb      = (unsigned short*)(ws + off); off += WB;
    int*            gcur    = (int*)(ws + off);            off += GB;
    unsigned int*   regions = (unsigned int*)(ws + off);   off += RB;
    (void)ws_size;

    init_kernel<<<8, 256, 0, stream>>>(gcur, (const unsigned int*)pos_e, flag);

    prep_kernel<<<BINB + 25 + 512, 256, 0, stream>>>(
        (const float4*)x, (uint2*)xb, W, wb, pos_e, neg_e, flag, gcur, regions);

    aggemm_kernel<<<NBUK, 512, 0, stream>>>(
        (const char*)xb, gcur, regions, wb, bias, out);
}